// Round 1
// 427.531 us; speedup vs baseline: 1.0003x; 1.0003x over previous
//
#include <hip/hip_runtime.h>

// DeltaNet fused pipeline, round 6:
//   k_cast:    x fp32 -> bf16
//   k_transw:  Wq/Wk/Wv -> Wt (N x K bf16), Wo -> Wot, Wg -> Wgt16 (z==4)
//   k_gemm256: NEW 256x256 8-phase bf16 MFMA GEMM for the QKV projection.
//              8 waves, BK=64, 128KB LDS double-buffer, half-tile staging 6
//              ahead with counted s_waitcnt vmcnt(4) at K-tile boundaries,
//              raw s_barrier (no vmcnt drain), setprio(1) around MFMA
//              clusters, XOR bank swizzle (phys slot = logical ^ (row&7)).
//   k_gemm:    old 128x128 kernel kept for the out-projection (N=2048 would
//              only fill 128 blocks at 256^2 -> no win there)
//   k_betaW:   wave-per-row dot: beta = clip(sigmoid(xb . Wgt16[h] + bg))
//   k_prep:    G-scan + RoPE + phi + scale + K^T transpose + intra-chunk A
//   k_scan:    sequential 32-chunk scan, state fp32 in MFMA accumulators
//   k_gemm:    out = numerb @ Wot + bo

typedef __attribute__((ext_vector_type(8))) short short8;
typedef __attribute__((ext_vector_type(4))) float f32x4;

__device__ __forceinline__ unsigned short f2bf(float f) {
  unsigned u = __float_as_uint(f);
  u += 0x7fffu + ((u >> 16) & 1u);   // RNE
  return (unsigned short)(u >> 16);
}
__device__ __forceinline__ float bf2f(unsigned short s) {
  return __uint_as_float(((unsigned)s) << 16);
}
__device__ __forceinline__ float phi_elu1(float x) {
  return x > 0.f ? x + 1.f : expf(x);
}
// async global->LDS, 16B per lane; LDS dest = wave-uniform base + lane*16.
__device__ __forceinline__ void gl_lds16(const void* g, void* l) {
  __builtin_amdgcn_global_load_lds(
      (const __attribute__((address_space(1))) void*)g,
      (__attribute__((address_space(3))) void*)l, 16, 0, 0);
}
// raw workgroup barrier: does NOT drain vmcnt (prefetches stay in flight).
// asm memory fences pin LDS ops to their phase at IR level.
__device__ __forceinline__ void bar_raw() {
  asm volatile("" ::: "memory");
  __builtin_amdgcn_s_barrier();
  asm volatile("" ::: "memory");
}

// ---------------- cast x -> bf16 ----------------
__global__ __launch_bounds__(256)
void k_cast(const float* __restrict__ x, unsigned short* __restrict__ xb) {
  int i = (blockIdx.x * 256 + threadIdx.x) * 4;
  float4 f = *(const float4*)(x + i);
  uint2 p;
  p.x = (unsigned)f2bf(f.x) | ((unsigned)f2bf(f.y) << 16);
  p.y = (unsigned)f2bf(f.z) | ((unsigned)f2bf(f.w) << 16);
  *(uint2*)(xb + i) = p;
}

// ---------------- transpose+cast weights ----------------
// z 0..3: W (K x N) -> (N x K) bf16. z==4: Wg (2048x16) -> Wgt16 (16x2048).
__global__ __launch_bounds__(256)
void k_transw(const float* __restrict__ Wq, const float* __restrict__ Wk,
              const float* __restrict__ Wv, const float* __restrict__ Wo,
              const float* __restrict__ Wg,
              unsigned short* __restrict__ Wt, unsigned short* __restrict__ Wot,
              unsigned short* __restrict__ Wgt16) {
  const int z = blockIdx.z;
  if (z == 4) {
    if (blockIdx.y != 0) return;
    int idx = blockIdx.x * 256 + threadIdx.x;  // 8192 threads
    int h = idx >> 9, k4 = (idx & 511) * 4;
    uint2 p;
    p.x = (unsigned)f2bf(Wg[(k4 + 0) * 16 + h]) | ((unsigned)f2bf(Wg[(k4 + 1) * 16 + h]) << 16);
    p.y = (unsigned)f2bf(Wg[(k4 + 2) * 16 + h]) | ((unsigned)f2bf(Wg[(k4 + 3) * 16 + h]) << 16);
    *(uint2*)(Wgt16 + (size_t)h * 2048 + k4) = p;
    return;
  }
  const float* W = (z == 0) ? Wq : (z == 1) ? Wk : (z == 2) ? Wv : Wo;
  unsigned short* out = (z < 3) ? (Wt + (size_t)z * 2048 * 2048) : Wot;
  __shared__ float tile[64][65];
  const int n0 = blockIdx.x * 64;
  const int k0 = blockIdx.y * 64;
  const int tx = threadIdx.x & 63;
  const int ty = threadIdx.x >> 6;
#pragma unroll
  for (int rl = 0; rl < 16; ++rl) {
    int kk = rl * 4 + ty;
    tile[kk][tx] = W[(size_t)(k0 + kk) * 2048 + n0 + tx];
  }
  __syncthreads();
#pragma unroll
  for (int rl = 0; rl < 16; ++rl) {
    int nn = rl * 4 + ty;
    out[(size_t)(n0 + nn) * 2048 + k0 + tx] = f2bf(tile[tx][nn]);
  }
}

// ---------------- beta: wave-per-row bf16 dot + sigmoid + clip ----------------
__global__ __launch_bounds__(256)
void k_betaW(const unsigned short* __restrict__ xb, const unsigned short* __restrict__ Wgt16,
             const float* __restrict__ bg, float* __restrict__ beta) {
  const int w = threadIdx.x >> 6;
  const int lane = threadIdx.x & 63;
  const int m = blockIdx.x * 4 + w;
  const int h = lane & 15, kq = lane >> 4;
  const unsigned short* xr = xb + (size_t)m * 2048 + kq * 512;
  const unsigned short* wr = Wgt16 + (size_t)h * 2048 + kq * 512;
  float acc = 0.f;
#pragma unroll 8
  for (int i = 0; i < 64; ++i) {
    short8 xv = *(const short8*)(xr + i * 8);
    short8 wv = *(const short8*)(wr + i * 8);
#pragma unroll
    for (int j = 0; j < 8; ++j)
      acc = fmaf(bf2f((unsigned short)xv[j]), bf2f((unsigned short)wv[j]), acc);
  }
  acc += __shfl_xor(acc, 16, 64);
  acc += __shfl_xor(acc, 32, 64);
  if (lane < 16) {
    float v = acc + bg[h];
    float bv = 1.f / (1.f + expf(-v));
    beta[(size_t)m * 16 + h] = fminf(fmaxf(bv, 0.8f), 0.9995f);
  }
}

// ---------------- bf16 MFMA GEMM 128x128 (kept for out-projection) ----------------
template <bool OUT_BF16, bool ADD_BIAS>
__global__ __launch_bounds__(256)
void k_gemm(const unsigned short* __restrict__ A, const unsigned short* __restrict__ Bt,
            void* __restrict__ Cptr, const float* __restrict__ bias,
            int M, int N, int K, int ldA, int ldC) {
  __shared__ __align__(16) unsigned short As[128][64];  // 16KB
  __shared__ __align__(16) unsigned short Bs[128][64];  // 16KB
  const int tid = threadIdx.x;
  const int n0 = blockIdx.x * 128;
  const int m0 = blockIdx.y * 128;
  const int lane = tid & 63;
  const int w = tid >> 6;
  const int wm = w >> 1, wn = w & 1;
  const int q = lane >> 4, r = lane & 15;

  const int srow0 = w * 8 + (lane >> 3);
  const int scol = ((lane & 7) ^ ((lane >> 3) & 7)) * 8;

  f32x4 acc[4][4];
#pragma unroll
  for (int i = 0; i < 4; ++i)
#pragma unroll
    for (int j = 0; j < 4; ++j) acc[i][j] = (f32x4){0.f, 0.f, 0.f, 0.f};

  const unsigned short* A0 = A + (size_t)(m0 + srow0) * ldA + scol;
  const unsigned short* B0 = Bt + (size_t)(n0 + srow0) * K + scol;
  unsigned short* lA = &As[srow0][(lane & 7) * 8];
  unsigned short* lB = &Bs[srow0][(lane & 7) * 8];

  const int rsw = r & 7;

  for (int kt = 0; kt < K; kt += 64) {
    __syncthreads();
#pragma unroll
    for (int i = 0; i < 4; ++i) {
      gl_lds16(A0 + (size_t)i * 32 * ldA + kt, lA + i * 2048);
      gl_lds16(B0 + (size_t)i * 32 * K + kt, lB + i * 2048);
    }
    __syncthreads();
#pragma unroll
    for (int kk = 0; kk < 2; ++kk) {
      const int ps = ((kk * 4 + q) ^ rsw) * 8;
      short8 af[4], bfr[4];
#pragma unroll
      for (int i = 0; i < 4; ++i)
        af[i] = *(const short8*)&As[wm * 64 + i * 16 + r][ps];
#pragma unroll
      for (int j = 0; j < 4; ++j)
        bfr[j] = *(const short8*)&Bs[wn * 64 + j * 16 + r][ps];
#pragma unroll
      for (int i = 0; i < 4; ++i)
#pragma unroll
        for (int j = 0; j < 4; ++j)
          acc[i][j] = __builtin_amdgcn_mfma_f32_16x16x32_bf16(af[i], bfr[j], acc[i][j], 0, 0, 0);
    }
  }
#pragma unroll
  for (int i = 0; i < 4; ++i) {
#pragma unroll
    for (int j = 0; j < 4; ++j) {
#pragma unroll
      for (int rr = 0; rr < 4; ++rr) {
        int mi = m0 + wm * 64 + i * 16 + q * 4 + rr;
        int ni = n0 + wn * 64 + j * 16 + r;
        float val = acc[i][j][rr];
        if (ADD_BIAS) val += bias[ni];
        if (OUT_BF16)
          ((unsigned short*)Cptr)[(size_t)mi * ldC + ni] = f2bf(val);
        else
          ((float*)Cptr)[(size_t)mi * ldC + ni] = val;
      }
    }
  }
}

// ---------------- bf16 MFMA GEMM 256x256, 8-phase pipelined ----------------
// C[M,N] = A[M,K] @ Bt[N,K]^T. 512 threads = 8 waves (2M x 4N), per-wave
// output 128x64. BK=64. LDS = 2 dbuf slots x 4 regions (A0,A1,B0,B1) x
// [128][64] bf16 = 128KB. Staging order per K-tile: B0,B1,A0,A1; one
// half-tile (2 x global_load_lds 16B/thread) issued per phase, 6 half-tiles
// ahead. vmcnt(4) once per K-tile boundary => incoming K-tile fully landed,
// 2 half-tiles stay in flight across barriers. Hazard proof (steady state,
// half X=4t+p+6 staged at phase p of K-tile t):
//   p=0 -> A0(t+1): opposite slot, no conflict.
//   p=1 -> A1(t+1): opposite slot.
//   p=2 -> B0(t+2): same slot, region last read at p=0 (B cached in regs).
//   p=3 -> B1(t+2): same slot, region last read at p=0.
//   A regions of slot t overwritten only at phases of K-tile t+1 (barrier-
//   separated from their p=3 reads).
template <bool OUT_BF16, bool ADD_BIAS>
__global__ __launch_bounds__(512, 2)
void k_gemm256(const unsigned short* __restrict__ A, const unsigned short* __restrict__ Bt,
               void* __restrict__ Cptr, const float* __restrict__ bias,
               int M, int N, int K, int ldA, int ldC) {
  // regions: 0 = A rows 0-127, 1 = A rows 128-255, 2 = B rows 0-127, 3 = B rows 128-255
  __shared__ __align__(16) unsigned short Ls[2][4][128][64];  // 128KB
  const int tid = threadIdx.x;
  const int lane = tid & 63;
  const int w = tid >> 6;       // 0..7
  const int wm = w >> 2;        // 0..1  (row half)
  const int wn = w & 3;         // 0..3  (64-col slice)
  const int ql = lane >> 4;     // 0..3
  const int r = lane & 15;
  const int n0 = blockIdx.x * 256;
  const int m0 = blockIdx.y * 256;

  // staging geometry: thread stages rows (i*64 + srow), phys slot sphys,
  // fetching logical col slot slog = sphys ^ (row&7)  (XOR bank swizzle).
  const int srow = tid >> 3;            // 0..63
  const int sphys = tid & 7;
  const int slog = sphys ^ (srow & 7);
  const unsigned short* Abase = A + (size_t)(m0 + srow) * ldA + slog * 8;
  const unsigned short* Bbase = Bt + (size_t)(n0 + srow) * K + slog * 8;

#define STAGE256(Xv)                                                          \
  do {                                                                        \
    const int Xh = (Xv);                                                      \
    const int tx = Xh >> 2, jx = Xh & 3;                                      \
    const size_t ldx = (jx < 2) ? (size_t)K : (size_t)ldA;                    \
    const unsigned short* gsrc =                                              \
        ((jx < 2) ? Bbase : Abase) + (size_t)((jx & 1) * 128) * ldx +         \
        (size_t)tx * 64;                                                      \
    unsigned short* ldst = &Ls[tx & 1][jx ^ 2][srow][sphys * 8];              \
    gl_lds16(gsrc, ldst);                                                     \
    gl_lds16(gsrc + 64 * ldx, ldst + 64 * 64);                                \
  } while (0)

  f32x4 acc[8][4];
#pragma unroll
  for (int i = 0; i < 8; ++i)
#pragma unroll
    for (int j = 0; j < 4; ++j) acc[i][j] = (f32x4){0.f, 0.f, 0.f, 0.f};

  const int NT = K >> 6;

  // prologue: stage halves 0..5 (K-tile 0 complete + B halves of K-tile 1)
  for (int X = 0; X < 6; ++X) STAGE256(X);
  asm volatile("s_waitcnt vmcnt(4)" ::: "memory");  // K-tile 0 landed
  bar_raw();

  short8 bfr[4][2];  // wave's B fragments for current K-tile, cached at p=0

  for (int t = 0; t < NT; ++t) {
    const int slt = t & 1;
    const unsigned short (*LA)[64] = Ls[slt][wm];
    const unsigned short (*LB)[64] = Ls[slt][2 + (wn >> 1)];
    const int brow0 = (wn & 1) * 64;
#pragma unroll
    for (int p = 0; p < 4; ++p) {
      // ---- ds_read section ----
      if (p == 0) {
#pragma unroll
        for (int nj = 0; nj < 4; ++nj)
#pragma unroll
          for (int kk = 0; kk < 2; ++kk)
            bfr[nj][kk] = *(const short8*)
                &LB[brow0 + nj * 16 + r][((kk * 4 + ql) ^ (r & 7)) * 8];
      }
      short8 af[2][2];
#pragma unroll
      for (int im = 0; im < 2; ++im)
#pragma unroll
        for (int kk = 0; kk < 2; ++kk)
          af[im][kk] = *(const short8*)
              &LA[(2 * p + im) * 16 + r][((kk * 4 + ql) ^ (r & 7)) * 8];
      // ---- stage section: one half-tile, 6 ahead ----
      {
        const int X = 4 * t + p + 6;
        if (X < 4 * NT) STAGE256(X);
      }
      // ---- mid barrier, then MFMA cluster ----
      bar_raw();
      __builtin_amdgcn_s_setprio(1);
#pragma unroll
      for (int kk = 0; kk < 2; ++kk)
#pragma unroll
        for (int im = 0; im < 2; ++im)
#pragma unroll
          for (int nj = 0; nj < 4; ++nj)
            acc[2 * p + im][nj] = __builtin_amdgcn_mfma_f32_16x16x32_bf16(
                af[im][kk], bfr[nj][kk], acc[2 * p + im][nj], 0, 0, 0);
      __builtin_amdgcn_s_setprio(0);
      if (p == 3) asm volatile("s_waitcnt vmcnt(4)" ::: "memory");
      bar_raw();
    }
  }
#undef STAGE256

  // ---- epilogue: C write ----
#pragma unroll
  for (int mi = 0; mi < 8; ++mi) {
#pragma unroll
    for (int nj = 0; nj < 4; ++nj) {
#pragma unroll
      for (int rr = 0; rr < 4; ++rr) {
        int mrow = m0 + wm * 128 + mi * 16 + ql * 4 + rr;
        int ncol = n0 + wn * 64 + nj * 16 + r;
        float val = acc[mi][nj][rr];
        if (ADD_BIAS) val += bias[ncol];
        if (OUT_BF16)
          ((unsigned short*)Cptr)[(size_t)mrow * ldC + ncol] = f2bf(val);
        else
          ((float*)Cptr)[(size_t)mrow * ldC + ncol] = val;
      }
    }
  }
}

// ---------------- prep: G-scan + RoPE + phi + scale + transpose + intra-chunk A ----------------
__global__ __launch_bounds__(256)
void k_prep(const unsigned short* __restrict__ qkv, const float* __restrict__ beta,
            unsigned short* __restrict__ Qt, unsigned short* __restrict__ Ktg,
            unsigned short* __restrict__ Ag, float* __restrict__ gch) {
  const int ch = blockIdx.x;
  const int bh = blockIdx.y;
  const int b = bh >> 4, h = bh & 15;
  const int tid = threadIdx.x;
  const int t0 = ch * 64;

  __shared__ float Gs[64];
  __shared__ unsigned short Qs[64][136];
  __shared__ unsigned short Ks[64][136];

  if (tid < 64) {
    float bb = beta[((size_t)(b * 2048 + t0 + tid)) * 16 + h];
#pragma unroll
    for (int off = 1; off < 64; off <<= 1) {
      float o = __shfl_up(bb, off, 64);
      if (tid >= off) bb *= o;
    }
    Gs[tid] = bb;
    if (tid == 63) gch[bh * 32 + ch] = bb;
  }
  __syncthreads();

  const int dgl = tid & 7;
  float invf[8];
#pragma unroll
  for (int j = 0; j < 8; ++j)
    invf[j] = expf((float)(dgl * 8 + j) * -0.14391156831212787f);  // 10000^(-e/64)

  int s = tid >> 3;
#pragma unroll
  for (int rep = 0; rep < 2; ++rep, s += 32) {
    size_t row = ((size_t)(b * 2048 + t0 + s)) * 6144 + (size_t)h * 128;
    short8 qlo = *(const short8*)(qkv + row + dgl * 8);
    short8 qhi = *(const short8*)(qkv + row + 64 + dgl * 8);
    short8 klo = *(const short8*)(qkv + row + 2048 + dgl * 8);
    short8 khi = *(const short8*)(qkv + row + 2048 + 64 + dgl * 8);
    float g = Gs[s];
    float ig = 1.f / g;
    float tg = (float)(t0 + s);
    short8 oql, oqh, okl, okh;
#pragma unroll
    for (int j = 0; j < 8; ++j) {
      float sn, cs;
      __sincosf(tg * invf[j], &sn, &cs);
      float qe = bf2f((unsigned short)qlo[j]), qo = bf2f((unsigned short)qhi[j]);
      float a0 = qe * cs - qo * sn, a1 = qe * sn + qo * cs;
      oql[j] = (short)f2bf(phi_elu1(a0) * g);
      oqh[j] = (short)f2bf(phi_elu1(a1) * g);
      float ke = bf2f((unsigned short)klo[j]), ko = bf2f((unsigned short)khi[j]);
      a0 = ke * cs - ko * sn;
      a1 = ke * sn + ko * cs;
      okl[j] = (short)f2bf(phi_elu1(a0) * ig);
      okh[j] = (short)f2bf(phi_elu1(a1) * ig);
    }
    size_t qbase = (((size_t)bh * 32 + ch) * 64 + s) * 128;
    *(short8*)(Qt + qbase + dgl * 8) = oql;
    *(short8*)(Qt + qbase + 64 + dgl * 8) = oqh;
    *(short8*)&Qs[s][dgl * 8] = oql;
    *(short8*)&Qs[s][64 + dgl * 8] = oqh;
    *(short8*)&Ks[s][dgl * 8] = okl;
    *(short8*)&Ks[s][64 + dgl * 8] = okh;
  }
  __syncthreads();

  {
    const int d = tid >> 1, sh = tid & 1;
    unsigned pk[16];
#pragma unroll
    for (int i = 0; i < 16; ++i)
      pk[i] = (unsigned)Ks[sh * 32 + 2 * i][d] | ((unsigned)Ks[sh * 32 + 2 * i + 1][d] << 16);
    unsigned short* kr = Ktg + ((size_t)bh * 32 + ch) * 8192 + (size_t)d * 64 + sh * 32;
#pragma unroll
    for (int i = 0; i < 4; ++i)
      *(uint4*)(kr + i * 8) = *(uint4*)&pk[i * 4];
  }

  {
    const int lane = tid & 63;
    const int w = tid >> 6;
    const int q = lane >> 4, r = lane & 15;
    f32x4 acc[4];
#pragma unroll
    for (int nt = 0; nt < 4; ++nt) acc[nt] = (f32x4){0.f, 0.f, 0.f, 0.f};
#pragma unroll
    for (int kk = 0; kk < 4; ++kk) {
      short8 af = *(const short8*)&Qs[w * 16 + r][kk * 32 + q * 8];
#pragma unroll
      for (int nt = 0; nt < 4; ++nt) {
        short8 bf = *(const short8*)&Ks[nt * 16 + r][kk * 32 + q * 8];
        acc[nt] = __builtin_amdgcn_mfma_f32_16x16x32_bf16(af, bf, acc[nt], 0, 0, 0);
      }
    }
    unsigned short* Agp = Ag + ((size_t)bh * 32 + ch) * 4096;
#pragma unroll
    for (int nt = 0; nt < 4; ++nt) {
#pragma unroll
      for (int rr = 0; rr < 4; ++rr) {
        int t_l = w * 16 + q * 4 + rr;
        int s_l = nt * 16 + r;
        float val = (s_l <= t_l) ? acc[nt][rr] : 0.f;
        Agp[t_l * 64 + s_l] = f2bf(val);
      }
    }
  }
}

// ---------------- chunk scan with fused denominator ----------------
// grid (8 eb, 32 bh). z-state fp32 in LDS (double-buffered).
__global__ __launch_bounds__(256)
void k_scan(const unsigned short* __restrict__ Qt, const unsigned short* __restrict__ Ktg,
            const unsigned short* __restrict__ Ag, const unsigned short* __restrict__ qkv,
            const float* __restrict__ gch, unsigned short* __restrict__ numerb) {
  const int eb = blockIdx.x;
  const int bh = blockIdx.y;
  const int b = bh >> 4, h = bh & 15;
  const int tid = threadIdx.x;
  const int lane = tid & 63;
  const int w = tid >> 6;
  const int q = lane >> 4, r = lane & 15;
  const int e0 = eb * 16;

  __shared__ unsigned short Qs[64][136];
  __shared__ unsigned short Kts[128][72];
  __shared__ unsigned short As[64][72];
  __shared__ unsigned short Vt[16][72];
  __shared__ unsigned short SbT[16][136];      // state readout, transposed [e][d]
  __shared__ __align__(16) float zbuf[2][128]; // z-state fp32, double-buffered

  f32x4 S_acc[2];
  S_acc[0] = (f32x4){0.f, 0.f, 0.f, 0.f};
  S_acc[1] = (f32x4){0.f, 0.f, 0.f, 0.f};
  if (tid < 128) zbuf[0][tid] = 0.f;

  for (int ch = 0; ch < 32; ++ch) {
    const int cur = ch & 1, nxt = cur ^ 1;
    __syncthreads();
    {
      const unsigned short* Qg = Qt + ((size_t)bh * 32 + ch) * 8192;
#pragma unroll
      for (int i = 0; i < 4; ++i) {
        int c = tid + i * 256;
        int ss = c >> 4, dg = c & 15;
        *(int4*)&Qs[ss][dg * 8] = *(const int4*)(Qg + ss * 128 + dg * 8);
      }
      const unsigned short* Kg = Ktg + ((size_t)bh * 32 + ch) * 8192;
#pragma unroll
      for (int i = 0; i < 4; ++i) {
        int c = tid + i * 256;
        int d = c >> 3, sg = c & 7;
        *(int4*)&Kts[d][sg * 8] = *(const int4*)(Kg + d * 64 + sg * 8);
      }
      const unsigned short* Agp = Ag + ((size_t)bh * 32 + ch) * 4096;
#pragma unroll
      for (int i = 0; i < 2; ++i) {
        int c = tid + i * 256;
        int t_l = c >> 3, sg = c & 7;
        *(int4*)&As[t_l][sg * 8] = *(const int4*)(Agp + t_l * 64 + sg * 8);
      }
      {
        int ss = tid >> 2, e4 = tid & 3;
        const unsigned short* vp =
            qkv + ((size_t)(b * 2048 + ch * 64 + ss)) * 6144 + 4096 + h * 128 + e0 + e4 * 4;
        uint2 vv = *(const uint2*)vp;
        const unsigned short* pv = (const unsigned short*)&vv;
#pragma unroll
        for (int j = 0; j < 4; ++j) Vt[e4 * 4 + j][ss] = pv[j];
      }
#pragma unroll
      for (int i = 0; i < 2; ++i)
#pragma unroll
        for (int rr = 0; rr < 4; ++rr)
          SbT[r][(2 * w + i) * 16 + q * 4 + rr] = f2bf(S_acc[i][rr]);
    }
    __syncthreads();

    const float gc = gch[bh * 32 + ch];

    // numer rows w*16..w*16+15: Qt @ S0 + A @ V ; denom = rowsum(A) + Qt . z0
    f32x4 nacc = (f32x4){0.f, 0.f, 0.f, 0.f};
    float dsum = 0.f;
#pragma unroll
    for (int kk = 0; kk < 4; ++kk) {
      short8 af = *(const short8*)&Qs[w * 16 + r][kk * 32 + q * 8];
      short8 bf = *(const short8*)&SbT[r][kk * 32 + q * 8];
      nacc = __builtin_amdgcn_mfma_f32_16x16x32_bf16(af, bf, nacc, 0, 0, 0);
      const float* zp = &zbuf[cur][kk * 32 + q * 8];
      float4 z0a = *(const float4*)zp;
      float4 z0b = *(const float4*)(zp + 4);
      dsum = fmaf(bf2f((unsigned short)af[0]), z0a.x, dsum);
      dsum = fmaf(bf2f((unsigned short)af[1]), z0a.y, dsum);
      dsum = fmaf(bf2f((unsigned short)af[2]), z0a.z, dsum);
      dsum = fmaf(bf2f((unsigned short)af[3]), z0a.w, dsum);
      dsum = fmaf(bf2f((unsigned short)af[4]), z0b.x, dsum);
      dsum = fmaf(bf2f((unsigned short)af[5]), z0b.y, dsum);
      dsum = fmaf(bf2f((unsigned short)af[6]), z0b.z, dsum);
      dsum = fmaf(bf2f((unsigned short)af[7]), z0b.w, dsum);
    }
    short8 vf[2];
#pragma unroll
    for (int kk = 0; kk < 2; ++kk) {
      vf[kk] = *(const short8*)&Vt[r][kk * 32 + q * 8];
      short8 af = *(const short8*)&As[w * 16 + r][kk * 32 + q * 8];
      nacc = __builtin_amdgcn_mfma_f32_16x16x32_bf16(af, vf[kk], nacc, 0, 0, 0);
#pragma unroll
      for (int j = 0; j < 8; ++j) dsum += bf2f((unsigned short)af[j]);
    }
    // complete denom for row w*16+r, invert, broadcast to acc-lanes
    dsum += __shfl_xor(dsum, 16, 64);
    dsum += __shfl_xor(dsum, 32, 64);
    float inv = 1.f / (dsum + 1e-6f);
#pragma unroll
    for (int rr = 0; rr < 4; ++rr) {
      float inv_r = __shfl(inv, q * 4 + rr, 64);
      int t_l = w * 16 + q * 4 + rr;
      size_t m = (size_t)b * 2048 + ch * 64 + t_l;
      numerb[m * 2048 + h * 128 + e0 + r] = f2bf(nacc[rr] * inv_r);
    }

    // z update: z' = gc * (z0 + rowsum_s Kts[d][s])
    {
      int d = tid >> 1, half = tid & 1;
      const unsigned short* kp = &Kts[d][half * 32];
      float zs = 0.f;
#pragma unroll
      for (int i = 0; i < 4; ++i) {
        short8 kv = *(const short8*)(kp + i * 8);
#pragma unroll
        for (int j = 0; j < 8; ++j) zs += bf2f((unsigned short)kv[j]);
      }
      zs += __shfl_xor(zs, 1, 64);
      if (half == 0) zbuf[nxt][d] = gc * (zbuf[cur][d] + zs);
    }

    // state update: S = gc * (S0 + Kt^T V)
#pragma unroll
    for (int i = 0; i < 2; ++i) {
#pragma unroll
      for (int kk = 0; kk < 2; ++kk) {
        short8 af = *(const short8*)&Kts[(2 * w + i) * 16 + r][kk * 32 + q * 8];
        S_acc[i] = __builtin_amdgcn_mfma_f32_16x16x32_bf16(af, vf[kk], S_acc[i], 0, 0, 0);
      }
#pragma unroll
      for (int rr = 0; rr < 4; ++rr) S_acc[i][rr] *= gc;
    }
  }
}

extern "C" void kernel_launch(void* const* d_in, const int* in_sizes, int n_in,
                              void* d_out, int out_size, void* d_ws, size_t ws_size,
                              hipStream_t stream) {
  const float* x  = (const float*)d_in[0];
  const float* Wq = (const float*)d_in[1];
  const float* Wk = (const float*)d_in[2];
  const float* Wv = (const float*)d_in[3];
  const float* Wg = (const float*)d_in[4];
  const float* bg = (const float*)d_in[5];
  const float* Wo = (const float*)d_in[6];
  const float* bo = (const float*)d_in[7];

  // workspace layout (bytes), total 134,742,016 (unchanged)
  char* ws = (char*)d_ws;
  unsigned short* xb    = (unsigned short*)(ws);             // 16.7MB: xb -> Qt
  unsigned short* Qt    = (unsigned short*)(ws);
  unsigned short* Wt    = (unsigned short*)(ws + 16777216);  // 25.2MB: Wt -> Ktg+Ag
  unsigned short* Ktg   = (unsigned short*)(ws + 16777216);
  unsigned short* Ag    = (unsigned short*)(ws + 33554432);
  unsigned short* Wot   = (unsigned short*)(ws + 41943040);  //  8.4MB
  unsigned short* qkvb  = (unsigned short*)(ws + 50331648);  // 50.3MB
  float*          beta  = (float*)(ws + 100663296);          //  0.26MB
  unsigned short* Wgt16 = (unsigned short*)(ws + 101187584); // 64KB (dead after betaW)
  unsigned short* numerb= (unsigned short*)(ws + 101187584); // 16.8MB bf16 (from scan on)
  // gchunk [32 bh][32 ch] fp32 = 4KB at head of d_out (fully overwritten by
  // the final out-projection GEMM afterwards).
  float*          gch   = (float*)d_out;

  k_cast<<<8192, 256, 0, stream>>>(x, xb);
  k_transw<<<dim3(32, 32, 5), 256, 0, stream>>>(Wq, Wk, Wv, Wo, Wg, Wt, Wot, Wgt16);
  k_gemm256<true, false><<<dim3(24, 16), 512, 0, stream>>>(
      xb, Wt, qkvb, nullptr, 4096, 6144, 2048, 2048, 6144);
  k_betaW<<<1024, 256, 0, stream>>>(xb, Wgt16, bg, beta);
  k_prep<<<dim3(32, 32), 256, 0, stream>>>(qkvb, beta, Qt, Ktg, Ag, gch);
  k_scan<<<dim3(8, 32), 256, 0, stream>>>(Qt, Ktg, Ag, qkvb, gch, numerb);
  k_gemm<false, true><<<dim3(16, 32), 256, 0, stream>>>(
      numerb, Wot, d_out, bo, 4096, 2048, 2048, 2048, 2048);
}

// Round 2
// 426.622 us; speedup vs baseline: 1.0024x; 1.0021x over previous
//
#include <hip/hip_runtime.h>

// DeltaNet fused pipeline, round 7:
//   k_cast:    x fp32 -> bf16
//   k_transw:  Wq/Wk/Wv -> Wt (N x K bf16), Wo -> Wot, Wg -> Wgt16 (z==4)
//   k_gemm2:   NEW 256x128-tile bf16 MFMA GEMM used for BOTH projections.
//              8 waves (4M x 2N), wave output 64x64, BK=64. LDS = 3 slots x
//              {A0,A1,B} x [128][64] bf16 = 144KB triple-buffer: tile t+2
//              staged during tile t => vmcnt(6) drains loads issued a full
//              K-tile earlier (latency hidden, 3 half-tiles in flight).
//              2 sub-phases x 16 MFMA per K-tile, raw barriers (no vmcnt
//              drain), lgkmcnt(0)+sched_barrier before MFMA, setprio(1)
//              around MFMA, XOR bank swizzle (phys = logical ^ (row&7)),
//              bijective XCD swizzle.
//              QKV grid 16x48 = 768 blocks = 3 exact rounds (no tail);
//              out-proj grid 16x16 = 256 blocks = 1 exact round.
//   k_betaW:   wave-per-row dot: beta = clip(sigmoid(xb . Wgt16[h] + bg))
//   k_prep:    G-scan + RoPE + phi + scale + K^T transpose + intra-chunk A
//   k_scan:    sequential 32-chunk scan, state fp32 in MFMA accumulators

typedef __attribute__((ext_vector_type(8))) short short8;
typedef __attribute__((ext_vector_type(4))) float f32x4;

__device__ __forceinline__ unsigned short f2bf(float f) {
  unsigned u = __float_as_uint(f);
  u += 0x7fffu + ((u >> 16) & 1u);   // RNE
  return (unsigned short)(u >> 16);
}
__device__ __forceinline__ float bf2f(unsigned short s) {
  return __uint_as_float(((unsigned)s) << 16);
}
__device__ __forceinline__ float phi_elu1(float x) {
  return x > 0.f ? x + 1.f : expf(x);
}
// async global->LDS, 16B per lane; LDS dest = wave-uniform base + lane*16.
__device__ __forceinline__ void gl_lds16(const void* g, void* l) {
  __builtin_amdgcn_global_load_lds(
      (const __attribute__((address_space(1))) void*)g,
      (__attribute__((address_space(3))) void*)l, 16, 0, 0);
}
// raw workgroup barrier: does NOT drain vmcnt (prefetches stay in flight).
__device__ __forceinline__ void bar_raw() {
  asm volatile("" ::: "memory");
  __builtin_amdgcn_s_barrier();
  asm volatile("" ::: "memory");
}

// ---------------- cast x -> bf16 ----------------
__global__ __launch_bounds__(256)
void k_cast(const float* __restrict__ x, unsigned short* __restrict__ xb) {
  int i = (blockIdx.x * 256 + threadIdx.x) * 4;
  float4 f = *(const float4*)(x + i);
  uint2 p;
  p.x = (unsigned)f2bf(f.x) | ((unsigned)f2bf(f.y) << 16);
  p.y = (unsigned)f2bf(f.z) | ((unsigned)f2bf(f.w) << 16);
  *(uint2*)(xb + i) = p;
}

// ---------------- transpose+cast weights ----------------
// z 0..3: W (K x N) -> (N x K) bf16. z==4: Wg (2048x16) -> Wgt16 (16x2048).
__global__ __launch_bounds__(256)
void k_transw(const float* __restrict__ Wq, const float* __restrict__ Wk,
              const float* __restrict__ Wv, const float* __restrict__ Wo,
              const float* __restrict__ Wg,
              unsigned short* __restrict__ Wt, unsigned short* __restrict__ Wot,
              unsigned short* __restrict__ Wgt16) {
  const int z = blockIdx.z;
  if (z == 4) {
    if (blockIdx.y != 0) return;
    int idx = blockIdx.x * 256 + threadIdx.x;  // 8192 threads
    int h = idx >> 9, k4 = (idx & 511) * 4;
    uint2 p;
    p.x = (unsigned)f2bf(Wg[(k4 + 0) * 16 + h]) | ((unsigned)f2bf(Wg[(k4 + 1) * 16 + h]) << 16);
    p.y = (unsigned)f2bf(Wg[(k4 + 2) * 16 + h]) | ((unsigned)f2bf(Wg[(k4 + 3) * 16 + h]) << 16);
    *(uint2*)(Wgt16 + (size_t)h * 2048 + k4) = p;
    return;
  }
  const float* W = (z == 0) ? Wq : (z == 1) ? Wk : (z == 2) ? Wv : Wo;
  unsigned short* out = (z < 3) ? (Wt + (size_t)z * 2048 * 2048) : Wot;
  __shared__ float tile[64][65];
  const int n0 = blockIdx.x * 64;
  const int k0 = blockIdx.y * 64;
  const int tx = threadIdx.x & 63;
  const int ty = threadIdx.x >> 6;
#pragma unroll
  for (int rl = 0; rl < 16; ++rl) {
    int kk = rl * 4 + ty;
    tile[kk][tx] = W[(size_t)(k0 + kk) * 2048 + n0 + tx];
  }
  __syncthreads();
#pragma unroll
  for (int rl = 0; rl < 16; ++rl) {
    int nn = rl * 4 + ty;
    out[(size_t)(n0 + nn) * 2048 + k0 + tx] = f2bf(tile[tx][nn]);
  }
}

// ---------------- beta: wave-per-row bf16 dot + sigmoid + clip ----------------
__global__ __launch_bounds__(256)
void k_betaW(const unsigned short* __restrict__ xb, const unsigned short* __restrict__ Wgt16,
             const float* __restrict__ bg, float* __restrict__ beta) {
  const int w = threadIdx.x >> 6;
  const int lane = threadIdx.x & 63;
  const int m = blockIdx.x * 4 + w;
  const int h = lane & 15, kq = lane >> 4;
  const unsigned short* xr = xb + (size_t)m * 2048 + kq * 512;
  const unsigned short* wr = Wgt16 + (size_t)h * 2048 + kq * 512;
  float acc = 0.f;
#pragma unroll 8
  for (int i = 0; i < 64; ++i) {
    short8 xv = *(const short8*)(xr + i * 8);
    short8 wv = *(const short8*)(wr + i * 8);
#pragma unroll
    for (int j = 0; j < 8; ++j)
      acc = fmaf(bf2f((unsigned short)xv[j]), bf2f((unsigned short)wv[j]), acc);
  }
  acc += __shfl_xor(acc, 16, 64);
  acc += __shfl_xor(acc, 32, 64);
  if (lane < 16) {
    float v = acc + bg[h];
    float bv = 1.f / (1.f + expf(-v));
    beta[(size_t)m * 16 + h] = fminf(fmaxf(bv, 0.8f), 0.9995f);
  }
}

// ---------------- bf16 MFMA GEMM 256x128, triple-buffered pipeline ----------------
// C[M,N] = A[M,K] @ Bt[N,K]^T. 512 threads = 8 waves (4M x 2N), per-wave
// output 64x64 (acc[4][4]). BK=64. LDS slots: Ls[slot][region][128][64],
// region 0 = A rows 0-127, 1 = A rows 128-255, 2 = B rows 0-127.
// Pipeline: during K-tile t we stage tile t+2 into slot (t+2)%3 (A halves at
// sub-phase 0, B at sub-phase 1). At end of tile t, vmcnt(6) drains tile
// t+1's 6 loads (issued during t-1: full-tile latency margin) keeping t+2's
// 6 in flight. Write-after-read safe: slot (t+2)%3 == slot (t-1)%3, whose
// readers finished before tile t began (barrier-separated; loads issued in
// program order during t cannot land earlier).
template <bool OUT_BF16, bool ADD_BIAS>
__global__ __launch_bounds__(512, 2)
void k_gemm2(const unsigned short* __restrict__ A, const unsigned short* __restrict__ Bt,
             void* __restrict__ Cptr, const float* __restrict__ bias,
             int M, int N, int K, int ldA, int ldC) {
  __shared__ __align__(16) unsigned short Ls[3][3][128][64];  // 144KB
  const int tid = threadIdx.x;
  const int lane = tid & 63;
  const int w = tid >> 6;    // 0..7
  const int wm = w >> 1;     // 0..3  (64-row slice of the 256 M-tile)
  const int wn = w & 1;      // 0..1  (64-col slice of the 128 N-tile)
  const int ql = lane >> 4;  // 0..3
  const int r = lane & 15;

  // bijective XCD swizzle (nwg % 8 == 0 for both call sites: 768, 256).
  // Each XCD gets a contiguous chunk of N-panels (B stays L2-resident).
  const int nwg = gridDim.x * gridDim.y;
  const int orig = blockIdx.y * gridDim.x + blockIdx.x;
  const int li = (orig & 7) * (nwg >> 3) + (orig >> 3);
  const int m0 = (li & 15) * 256;   // gridDim.x == 16 (M/256)
  const int n0 = (li >> 4) * 128;

  // staging: thread stages rows (i*64 + srow), phys slot sphys, fetching
  // logical col slot slog = sphys ^ (srow&7)  (XOR bank swizzle; (64+s)&7 == s&7).
  const int srow = tid >> 3;   // 0..63
  const int sphys = tid & 7;
  const int slog = sphys ^ (srow & 7);
  const unsigned short* Ab = A + (size_t)(m0 + srow) * ldA + slog * 8;
  const unsigned short* Bb = Bt + (size_t)(n0 + srow) * K + slog * 8;

  // stage region h (0 = A rows 0-127, 1 = A rows 128-255, 2 = B) of K-tile tt
#define STG(st, h, tt)                                                        \
  do {                                                                        \
    const size_t ldx = ((h) == 2) ? (size_t)K : (size_t)ldA;                  \
    const unsigned short* gs =                                                \
        (((h) == 2) ? Bb : (Ab + (size_t)((h) * 128) * ldA)) +                \
        (size_t)(tt) * 64;                                                    \
    unsigned short* ld = &Ls[(st)][(h)][srow][sphys * 8];                     \
    gl_lds16(gs, ld);                                                         \
    gl_lds16(gs + 64 * ldx, ld + 64 * 64);                                    \
  } while (0)

  f32x4 acc[4][4];
#pragma unroll
  for (int i = 0; i < 4; ++i)
#pragma unroll
    for (int j = 0; j < 4; ++j) acc[i][j] = (f32x4){0.f, 0.f, 0.f, 0.f};

  const int NT = K >> 6;

  // prologue: stage K-tiles 0 and 1 (6 loads each)
#pragma unroll
  for (int h = 0; h < 3; ++h) STG(0, h, 0);
#pragma unroll
  for (int h = 0; h < 3; ++h) STG(1, h, 1);
  asm volatile("s_waitcnt vmcnt(6)" ::: "memory");  // tile 0 landed
  bar_raw();

  short8 bfr[4][2];  // wave's B fragments for current K-tile (cached at p=0)

  for (int t = 0; t < NT; ++t) {
    const int st = t % 3;
    const unsigned short (*LA)[64] = Ls[st][wm >> 1];
    const unsigned short (*LB)[64] = Ls[st][2];
    const int arow0 = (wm & 1) * 64;
    const int brow0 = wn * 64;
    const bool pf = (t + 2 < NT);
    const int s2 = (t + 2) % 3;
#pragma unroll
    for (int p = 0; p < 2; ++p) {
      // ---- ds_read section ----
      if (p == 0) {
#pragma unroll
        for (int nj = 0; nj < 4; ++nj)
#pragma unroll
          for (int kk = 0; kk < 2; ++kk)
            bfr[nj][kk] = *(const short8*)
                &LB[brow0 + nj * 16 + r][((kk * 4 + ql) ^ (r & 7)) * 8];
      }
      short8 af[2][2];
#pragma unroll
      for (int im = 0; im < 2; ++im)
#pragma unroll
        for (int kk = 0; kk < 2; ++kk)
          af[im][kk] = *(const short8*)
              &LA[arow0 + (p * 2 + im) * 16 + r][((kk * 4 + ql) ^ (r & 7)) * 8];
      // ---- stage section: prefetch K-tile t+2 ----
      if (pf) {
        if (p == 0) {
          STG(s2, 0, t + 2);
          STG(s2, 1, t + 2);
        } else {
          STG(s2, 2, t + 2);
        }
      }
      // ---- mid barrier, then MFMA cluster ----
      bar_raw();
      asm volatile("s_waitcnt lgkmcnt(0)" ::: "memory");
      __builtin_amdgcn_sched_barrier(0);
      __builtin_amdgcn_s_setprio(1);
#pragma unroll
      for (int kk = 0; kk < 2; ++kk)
#pragma unroll
        for (int im = 0; im < 2; ++im)
#pragma unroll
          for (int nj = 0; nj < 4; ++nj)
            acc[p * 2 + im][nj] = __builtin_amdgcn_mfma_f32_16x16x32_bf16(
                af[im][kk], bfr[nj][kk], acc[p * 2 + im][nj], 0, 0, 0);
      __builtin_amdgcn_s_setprio(0);
      if (p == 1) {
        // drain tile t+1's loads; keep t+2's (if any) in flight
        if (pf)
          asm volatile("s_waitcnt vmcnt(6)" ::: "memory");
        else if (t + 1 < NT)
          asm volatile("s_waitcnt vmcnt(0)" ::: "memory");
      }
      bar_raw();
    }
  }
#undef STG

  // ---- epilogue: C write ----
#pragma unroll
  for (int mi = 0; mi < 4; ++mi) {
#pragma unroll
    for (int nj = 0; nj < 4; ++nj) {
#pragma unroll
      for (int rr = 0; rr < 4; ++rr) {
        int mrow = m0 + wm * 64 + mi * 16 + ql * 4 + rr;
        int ncol = n0 + wn * 64 + nj * 16 + r;
        float val = acc[mi][nj][rr];
        if (ADD_BIAS) val += bias[ncol];
        if (OUT_BF16)
          ((unsigned short*)Cptr)[(size_t)mrow * ldC + ncol] = f2bf(val);
        else
          ((float*)Cptr)[(size_t)mrow * ldC + ncol] = val;
      }
    }
  }
}

// ---------------- prep: G-scan + RoPE + phi + scale + transpose + intra-chunk A ----------------
__global__ __launch_bounds__(256)
void k_prep(const unsigned short* __restrict__ qkv, const float* __restrict__ beta,
            unsigned short* __restrict__ Qt, unsigned short* __restrict__ Ktg,
            unsigned short* __restrict__ Ag, float* __restrict__ gch) {
  const int ch = blockIdx.x;
  const int bh = blockIdx.y;
  const int b = bh >> 4, h = bh & 15;
  const int tid = threadIdx.x;
  const int t0 = ch * 64;

  __shared__ float Gs[64];
  __shared__ unsigned short Qs[64][136];
  __shared__ unsigned short Ks[64][136];

  if (tid < 64) {
    float bb = beta[((size_t)(b * 2048 + t0 + tid)) * 16 + h];
#pragma unroll
    for (int off = 1; off < 64; off <<= 1) {
      float o = __shfl_up(bb, off, 64);
      if (tid >= off) bb *= o;
    }
    Gs[tid] = bb;
    if (tid == 63) gch[bh * 32 + ch] = bb;
  }
  __syncthreads();

  const int dgl = tid & 7;
  float invf[8];
#pragma unroll
  for (int j = 0; j < 8; ++j)
    invf[j] = expf((float)(dgl * 8 + j) * -0.14391156831212787f);  // 10000^(-e/64)

  int s = tid >> 3;
#pragma unroll
  for (int rep = 0; rep < 2; ++rep, s += 32) {
    size_t row = ((size_t)(b * 2048 + t0 + s)) * 6144 + (size_t)h * 128;
    short8 qlo = *(const short8*)(qkv + row + dgl * 8);
    short8 qhi = *(const short8*)(qkv + row + 64 + dgl * 8);
    short8 klo = *(const short8*)(qkv + row + 2048 + dgl * 8);
    short8 khi = *(const short8*)(qkv + row + 2048 + 64 + dgl * 8);
    float g = Gs[s];
    float ig = 1.f / g;
    float tg = (float)(t0 + s);
    short8 oql, oqh, okl, okh;
#pragma unroll
    for (int j = 0; j < 8; ++j) {
      float sn, cs;
      __sincosf(tg * invf[j], &sn, &cs);
      float qe = bf2f((unsigned short)qlo[j]), qo = bf2f((unsigned short)qhi[j]);
      float a0 = qe * cs - qo * sn, a1 = qe * sn + qo * cs;
      oql[j] = (short)f2bf(phi_elu1(a0) * g);
      oqh[j] = (short)f2bf(phi_elu1(a1) * g);
      float ke = bf2f((unsigned short)klo[j]), ko = bf2f((unsigned short)khi[j]);
      a0 = ke * cs - ko * sn;
      a1 = ke * sn + ko * cs;
      okl[j] = (short)f2bf(phi_elu1(a0) * ig);
      okh[j] = (short)f2bf(phi_elu1(a1) * ig);
    }
    size_t qbase = (((size_t)bh * 32 + ch) * 64 + s) * 128;
    *(short8*)(Qt + qbase + dgl * 8) = oql;
    *(short8*)(Qt + qbase + 64 + dgl * 8) = oqh;
    *(short8*)&Qs[s][dgl * 8] = oql;
    *(short8*)&Qs[s][64 + dgl * 8] = oqh;
    *(short8*)&Ks[s][dgl * 8] = okl;
    *(short8*)&Ks[s][64 + dgl * 8] = okh;
  }
  __syncthreads();

  {
    const int d = tid >> 1, sh = tid & 1;
    unsigned pk[16];
#pragma unroll
    for (int i = 0; i < 16; ++i)
      pk[i] = (unsigned)Ks[sh * 32 + 2 * i][d] | ((unsigned)Ks[sh * 32 + 2 * i + 1][d] << 16);
    unsigned short* kr = Ktg + ((size_t)bh * 32 + ch) * 8192 + (size_t)d * 64 + sh * 32;
#pragma unroll
    for (int i = 0; i < 4; ++i)
      *(uint4*)(kr + i * 8) = *(uint4*)&pk[i * 4];
  }

  {
    const int lane = tid & 63;
    const int w = tid >> 6;
    const int q = lane >> 4, r = lane & 15;
    f32x4 acc[4];
#pragma unroll
    for (int nt = 0; nt < 4; ++nt) acc[nt] = (f32x4){0.f, 0.f, 0.f, 0.f};
#pragma unroll
    for (int kk = 0; kk < 4; ++kk) {
      short8 af = *(const short8*)&Qs[w * 16 + r][kk * 32 + q * 8];
#pragma unroll
      for (int nt = 0; nt < 4; ++nt) {
        short8 bf = *(const short8*)&Ks[nt * 16 + r][kk * 32 + q * 8];
        acc[nt] = __builtin_amdgcn_mfma_f32_16x16x32_bf16(af, bf, acc[nt], 0, 0, 0);
      }
    }
    unsigned short* Agp = Ag + ((size_t)bh * 32 + ch) * 4096;
#pragma unroll
    for (int nt = 0; nt < 4; ++nt) {
#pragma unroll
      for (int rr = 0; rr < 4; ++rr) {
        int t_l = w * 16 + q * 4 + rr;
        int s_l = nt * 16 + r;
        float val = (s_l <= t_l) ? acc[nt][rr] : 0.f;
        Agp[t_l * 64 + s_l] = f2bf(val);
      }
    }
  }
}

// ---------------- chunk scan with fused denominator ----------------
// grid (8 eb, 32 bh). z-state fp32 in LDS (double-buffered).
__global__ __launch_bounds__(256)
void k_scan(const unsigned short* __restrict__ Qt, const unsigned short* __restrict__ Ktg,
            const unsigned short* __restrict__ Ag, const unsigned short* __restrict__ qkv,
            const float* __restrict__ gch, unsigned short* __restrict__ numerb) {
  const int eb = blockIdx.x;
  const int bh = blockIdx.y;
  const int b = bh >> 4, h = bh & 15;
  const int tid = threadIdx.x;
  const int lane = tid & 63;
  const int w = tid >> 6;
  const int q = lane >> 4, r = lane & 15;
  const int e0 = eb * 16;

  __shared__ unsigned short Qs[64][136];
  __shared__ unsigned short Kts[128][72];
  __shared__ unsigned short As[64][72];
  __shared__ unsigned short Vt[16][72];
  __shared__ unsigned short SbT[16][136];      // state readout, transposed [e][d]
  __shared__ __align__(16) float zbuf[2][128]; // z-state fp32, double-buffered

  f32x4 S_acc[2];
  S_acc[0] = (f32x4){0.f, 0.f, 0.f, 0.f};
  S_acc[1] = (f32x4){0.f, 0.f, 0.f, 0.f};
  if (tid < 128) zbuf[0][tid] = 0.f;

  for (int ch = 0; ch < 32; ++ch) {
    const int cur = ch & 1, nxt = cur ^ 1;
    __syncthreads();
    {
      const unsigned short* Qg = Qt + ((size_t)bh * 32 + ch) * 8192;
#pragma unroll
      for (int i = 0; i < 4; ++i) {
        int c = tid + i * 256;
        int ss = c >> 4, dg = c & 15;
        *(int4*)&Qs[ss][dg * 8] = *(const int4*)(Qg + ss * 128 + dg * 8);
      }
      const unsigned short* Kg = Ktg + ((size_t)bh * 32 + ch) * 8192;
#pragma unroll
      for (int i = 0; i < 4; ++i) {
        int c = tid + i * 256;
        int d = c >> 3, sg = c & 7;
        *(int4*)&Kts[d][sg * 8] = *(const int4*)(Kg + d * 64 + sg * 8);
      }
      const unsigned short* Agp = Ag + ((size_t)bh * 32 + ch) * 4096;
#pragma unroll
      for (int i = 0; i < 2; ++i) {
        int c = tid + i * 256;
        int t_l = c >> 3, sg = c & 7;
        *(int4*)&As[t_l][sg * 8] = *(const int4*)(Agp + t_l * 64 + sg * 8);
      }
      {
        int ss = tid >> 2, e4 = tid & 3;
        const unsigned short* vp =
            qkv + ((size_t)(b * 2048 + ch * 64 + ss)) * 6144 + 4096 + h * 128 + e0 + e4 * 4;
        uint2 vv = *(const uint2*)vp;
        const unsigned short* pv = (const unsigned short*)&vv;
#pragma unroll
        for (int j = 0; j < 4; ++j) Vt[e4 * 4 + j][ss] = pv[j];
      }
#pragma unroll
      for (int i = 0; i < 2; ++i)
#pragma unroll
        for (int rr = 0; rr < 4; ++rr)
          SbT[r][(2 * w + i) * 16 + q * 4 + rr] = f2bf(S_acc[i][rr]);
    }
    __syncthreads();

    const float gc = gch[bh * 32 + ch];

    // numer rows w*16..w*16+15: Qt @ S0 + A @ V ; denom = rowsum(A) + Qt . z0
    f32x4 nacc = (f32x4){0.f, 0.f, 0.f, 0.f};
    float dsum = 0.f;
#pragma unroll
    for (int kk = 0; kk < 4; ++kk) {
      short8 af = *(const short8*)&Qs[w * 16 + r][kk * 32 + q * 8];
      short8 bf = *(const short8*)&SbT[r][kk * 32 + q * 8];
      nacc = __builtin_amdgcn_mfma_f32_16x16x32_bf16(af, bf, nacc, 0, 0, 0);
      const float* zp = &zbuf[cur][kk * 32 + q * 8];
      float4 z0a = *(const float4*)zp;
      float4 z0b = *(const float4*)(zp + 4);
      dsum = fmaf(bf2f((unsigned short)af[0]), z0a.x, dsum);
      dsum = fmaf(bf2f((unsigned short)af[1]), z0a.y, dsum);
      dsum = fmaf(bf2f((unsigned short)af[2]), z0a.z, dsum);
      dsum = fmaf(bf2f((unsigned short)af[3]), z0a.w, dsum);
      dsum = fmaf(bf2f((unsigned short)af[4]), z0b.x, dsum);
      dsum = fmaf(bf2f((unsigned short)af[5]), z0b.y, dsum);
      dsum = fmaf(bf2f((unsigned short)af[6]), z0b.z, dsum);
      dsum = fmaf(bf2f((unsigned short)af[7]), z0b.w, dsum);
    }
    short8 vf[2];
#pragma unroll
    for (int kk = 0; kk < 2; ++kk) {
      vf[kk] = *(const short8*)&Vt[r][kk * 32 + q * 8];
      short8 af = *(const short8*)&As[w * 16 + r][kk * 32 + q * 8];
      nacc = __builtin_amdgcn_mfma_f32_16x16x32_bf16(af, vf[kk], nacc, 0, 0, 0);
#pragma unroll
      for (int j = 0; j < 8; ++j) dsum += bf2f((unsigned short)af[j]);
    }
    // complete denom for row w*16+r, invert, broadcast to acc-lanes
    dsum += __shfl_xor(dsum, 16, 64);
    dsum += __shfl_xor(dsum, 32, 64);
    float inv = 1.f / (dsum + 1e-6f);
#pragma unroll
    for (int rr = 0; rr < 4; ++rr) {
      float inv_r = __shfl(inv, q * 4 + rr, 64);
      int t_l = w * 16 + q * 4 + rr;
      size_t m = (size_t)b * 2048 + ch * 64 + t_l;
      numerb[m * 2048 + h * 128 + e0 + r] = f2bf(nacc[rr] * inv_r);
    }

    // z update: z' = gc * (z0 + rowsum_s Kts[d][s])
    {
      int d = tid >> 1, half = tid & 1;
      const unsigned short* kp = &Kts[d][half * 32];
      float zs = 0.f;
#pragma unroll
      for (int i = 0; i < 4; ++i) {
        short8 kv = *(const short8*)(kp + i * 8);
#pragma unroll
        for (int j = 0; j < 8; ++j) zs += bf2f((unsigned short)kv[j]);
      }
      zs += __shfl_xor(zs, 1, 64);
      if (half == 0) zbuf[nxt][d] = gc * (zbuf[cur][d] + zs);
    }

    // state update: S = gc * (S0 + Kt^T V)
#pragma unroll
    for (int i = 0; i < 2; ++i) {
#pragma unroll
      for (int kk = 0; kk < 2; ++kk) {
        short8 af = *(const short8*)&Kts[(2 * w + i) * 16 + r][kk * 32 + q * 8];
        S_acc[i] = __builtin_amdgcn_mfma_f32_16x16x32_bf16(af, vf[kk], S_acc[i], 0, 0, 0);
      }
#pragma unroll
      for (int rr = 0; rr < 4; ++rr) S_acc[i][rr] *= gc;
    }
  }
}

extern "C" void kernel_launch(void* const* d_in, const int* in_sizes, int n_in,
                              void* d_out, int out_size, void* d_ws, size_t ws_size,
                              hipStream_t stream) {
  const float* x  = (const float*)d_in[0];
  const float* Wq = (const float*)d_in[1];
  const float* Wk = (const float*)d_in[2];
  const float* Wv = (const float*)d_in[3];
  const float* Wg = (const float*)d_in[4];
  const float* bg = (const float*)d_in[5];
  const float* Wo = (const float*)d_in[6];
  const float* bo = (const float*)d_in[7];

  // workspace layout (bytes), total 134,742,016 (unchanged)
  char* ws = (char*)d_ws;
  unsigned short* xb    = (unsigned short*)(ws);             // 16.7MB: xb -> Qt
  unsigned short* Qt    = (unsigned short*)(ws);
  unsigned short* Wt    = (unsigned short*)(ws + 16777216);  // 25.2MB: Wt -> Ktg+Ag
  unsigned short* Ktg   = (unsigned short*)(ws + 16777216);
  unsigned short* Ag    = (unsigned short*)(ws + 33554432);
  unsigned short* Wot   = (unsigned short*)(ws + 41943040);  //  8.4MB
  unsigned short* qkvb  = (unsigned short*)(ws + 50331648);  // 50.3MB
  float*          beta  = (float*)(ws + 100663296);          //  0.26MB
  unsigned short* Wgt16 = (unsigned short*)(ws + 101187584); // 64KB (dead after betaW)
  unsigned short* numerb= (unsigned short*)(ws + 101187584); // 16.8MB bf16 (from scan on)
  // gchunk [32 bh][32 ch] fp32 = 4KB at head of d_out (fully overwritten by
  // the final out-projection GEMM afterwards).
  float*          gch   = (float*)d_out;

  k_cast<<<8192, 256, 0, stream>>>(x, xb);
  k_transw<<<dim3(32, 32, 5), 256, 0, stream>>>(Wq, Wk, Wv, Wo, Wg, Wt, Wot, Wgt16);
  // QKV: M=4096, N=6144 -> grid 16 x 48 = 768 blocks = 3 exact rounds.
  k_gemm2<true, false><<<dim3(16, 48), 512, 0, stream>>>(
      xb, Wt, qkvb, nullptr, 4096, 6144, 2048, 2048, 6144);
  k_betaW<<<1024, 256, 0, stream>>>(xb, Wgt16, bg, beta);
  k_prep<<<dim3(32, 32), 256, 0, stream>>>(qkvb, beta, Qt, Ktg, Ag, gch);
  k_scan<<<dim3(8, 32), 256, 0, stream>>>(Qt, Ktg, Ag, qkvb, gch, numerb);
  // out-proj: M=4096, N=2048 -> grid 16 x 16 = 256 blocks = 1 exact round.
  k_gemm2<false, true><<<dim3(16, 16), 512, 0, stream>>>(
      numerb, Wot, d_out, bo, 4096, 2048, 2048, 2048, 2048);
}